// Round 2
// baseline (670.696 us; speedup 1.0000x reference)
//
#include <hip/hip_runtime.h>

typedef __bf16 bf16;
typedef __bf16 bf16x8 __attribute__((ext_vector_type(8)));
typedef float f32x4 __attribute__((ext_vector_type(4)));

#define N_ROWS 65536

// padded weight shapes (row-major [out][k]), bf16, in d_ws
#define W1P_E  (208 * 768)
#define W12P_E (112 * 224)
#define W13P_E (112 * 128)
#define W2P_E  (512 * 128)
#define WP_TOTAL (W1P_E + W12P_E + W13P_E + W2P_E)   // 264704 elems
#define BP_OFF_BYTES (WP_TOTAL * 2)                  // 529408
#define BP_FLOATS 944                                // b1p[208] b12p[112] b13p[112] b2p[512]
#define ACC_OFF_BYTES (BP_OFF_BYTES + BP_FLOATS * 4) // 533184 (16B aligned)
#define ACC_FLOATS 259                               // [0..255] colsum, [256] p0, [257] S, [258] p3

// LDS physical strides (bf16 elems; row stride bytes divisible by 16)
#define X1_STRIDE 232
#define X23_STRIDE 136

__global__ void pack_kernel(const float* __restrict__ W1, const float* __restrict__ b1,
                            const float* __restrict__ W12, const float* __restrict__ b12,
                            const float* __restrict__ W13, const float* __restrict__ b13,
                            const float* __restrict__ W2, const float* __restrict__ b2,
                            bf16* __restrict__ wp, float* __restrict__ bp) {
  int i = blockIdx.x * 256 + threadIdx.x;
  if (i < WP_TOTAL) {
    float v = 0.0f;
    if (i < W1P_E) {
      int o = i / 768, k = i - o * 768;
      if (o < 200) v = W1[o * 768 + k];
    } else if (i < W1P_E + W12P_E) {
      int j = i - W1P_E;
      int o = j / 224, k = j - o * 224;
      if (o < 100 && k < 200) v = W12[o * 200 + k];
    } else if (i < W1P_E + W12P_E + W13P_E) {
      int j = i - (W1P_E + W12P_E);
      int o = j / 128, k = j - o * 128;
      if (o < 100 && k < 100) v = W13[o * 100 + k];
    } else {
      int j = i - (W1P_E + W12P_E + W13P_E);
      int o = j / 128, k = j - o * 128;
      if (k < 100) v = W2[o * 100 + k];
    }
    wp[i] = (bf16)v;
  } else {
    int j = i - WP_TOTAL;
    if (j < BP_FLOATS) {
      float v = 0.0f;
      if (j < 208)      { if (j < 200) v = b1[j]; }
      else if (j < 320) { int o = j - 208; if (o < 100) v = b12[o]; }
      else if (j < 432) { int o = j - 320; if (o < 100) v = b13[o]; }
      else              { v = b2[j - 432]; }
      bp[j] = v;
    }
  }
}

__device__ inline bf16x8 cvt8(const float* __restrict__ p) {
  f32x4 lo = *(const f32x4*)p;
  f32x4 hi = *(const f32x4*)(p + 4);
  bf16x8 r;
#pragma unroll
  for (int i = 0; i < 4; i++) { r[i] = (bf16)lo[i]; r[4 + i] = (bf16)hi[i]; }
  return r;
}

// One block = 4 waves = 64 rows; each wave runs 16 rows through all 4 layers.
// MFMA 16x16x32 bf16. A: lane holds A[m=lane&15][k=quad*8+j]. B: lane holds
// B[k=quad*8+j][n=lane&15] = W[n][k] (contiguous from W row). C/D: lane reg r
// holds D[row=quad*4+r][col=lane&15].
__global__ __launch_bounds__(256, 2) void mlp_main(
    const float* __restrict__ input, const float* __restrict__ h,
    const bf16* __restrict__ wp, const float* __restrict__ bp,
    float* __restrict__ out, float* __restrict__ p0_accum) {
  __shared__ __align__(16) bf16 x1s[4][16][X1_STRIDE];
  __shared__ __align__(16) bf16 x2s[4][16][X23_STRIDE];
  __shared__ __align__(16) bf16 x3s[4][16][X23_STRIDE];

  const int lane = threadIdx.x & 63;
  const int wave = threadIdx.x >> 6;
  const int c16 = lane & 15;
  const int quad = lane >> 4;
  const int m0 = blockIdx.x * 64 + wave * 16;

  const bf16* W1p  = wp;
  const bf16* W12p = wp + W1P_E;
  const bf16* W13p = wp + W1P_E + W12P_E;
  const bf16* W2p  = wp + W1P_E + W12P_E + W13P_E;
  const float* b1p  = bp;
  const float* b12p = bp + 208;
  const float* b13p = bp + 320;
  const float* b2p  = bp + 432;

  // ---------------- Layer 1: (16x768) @ W1p^T -> 16x208 ----------------
  f32x4 acc1[13];
#pragma unroll
  for (int t = 0; t < 13; t++) acc1[t] = (f32x4){0.f, 0.f, 0.f, 0.f};

  const float* arow_in = input + (size_t)(m0 + c16) * 512;
  const float* arow_h  = h + (size_t)(m0 + c16) * 256;
#pragma unroll
  for (int ks = 0; ks < 24; ks++) {
    const int k0 = ks * 32;
    bf16x8 a;
    if (k0 < 512) a = cvt8(arow_in + k0 + quad * 8);
    else          a = cvt8(arow_h + (k0 - 512) + quad * 8);
    const bf16* bb = W1p + (size_t)c16 * 768 + k0 + quad * 8;
#pragma unroll
    for (int t = 0; t < 13; t++) {
      bf16x8 b = *(const bf16x8*)(bb + t * 16 * 768);
      acc1[t] = __builtin_amdgcn_mfma_f32_16x16x32_bf16(a, b, acc1[t], 0, 0, 0);
    }
  }
#pragma unroll
  for (int t = 0; t < 13; t++) {
    const int o = t * 16 + c16;
    const float bias = b1p[o];
#pragma unroll
    for (int r = 0; r < 4; r++) {
      float v = acc1[t][r] + bias;
      v = fmaxf(v, 0.0f);
      x1s[wave][quad * 4 + r][o] = (bf16)v;
    }
  }
  // zero logical pad cols 208..223 (K2 padded to 224)
  for (int idx = lane; idx < 256; idx += 64)
    x1s[wave][idx >> 4][208 + (idx & 15)] = (bf16)0.0f;
  __syncthreads();

  // ---------------- Layer 2: (16x224) @ W12p^T -> 16x112 ----------------
  f32x4 acc2[7];
#pragma unroll
  for (int t = 0; t < 7; t++) acc2[t] = (f32x4){0.f, 0.f, 0.f, 0.f};
#pragma unroll
  for (int ks = 0; ks < 7; ks++) {
    const int k0 = ks * 32;
    bf16x8 a = *(const bf16x8*)&x1s[wave][c16][k0 + quad * 8];
    const bf16* bb = W12p + (size_t)c16 * 224 + k0 + quad * 8;
#pragma unroll
    for (int t = 0; t < 7; t++) {
      bf16x8 b = *(const bf16x8*)(bb + t * 16 * 224);
      acc2[t] = __builtin_amdgcn_mfma_f32_16x16x32_bf16(a, b, acc2[t], 0, 0, 0);
    }
  }
#pragma unroll
  for (int t = 0; t < 7; t++) {
    const int o = t * 16 + c16;
    const float bias = b12p[o];
#pragma unroll
    for (int r = 0; r < 4; r++) {
      float v = acc2[t][r] + bias;
      v = fmaxf(v, 0.0f);
      x2s[wave][quad * 4 + r][o] = (bf16)v;
    }
  }
  for (int idx = lane; idx < 256; idx += 64)
    x2s[wave][idx >> 4][112 + (idx & 15)] = (bf16)0.0f;
  __syncthreads();

  // ---------------- Layer 3: (16x128) @ W13p^T -> 16x112 ----------------
  f32x4 acc3[7];
#pragma unroll
  for (int t = 0; t < 7; t++) acc3[t] = (f32x4){0.f, 0.f, 0.f, 0.f};
#pragma unroll
  for (int ks = 0; ks < 4; ks++) {
    const int k0 = ks * 32;
    bf16x8 a = *(const bf16x8*)&x2s[wave][c16][k0 + quad * 8];
    const bf16* bb = W13p + (size_t)c16 * 128 + k0 + quad * 8;
#pragma unroll
    for (int t = 0; t < 7; t++) {
      bf16x8 b = *(const bf16x8*)(bb + t * 16 * 128);
      acc3[t] = __builtin_amdgcn_mfma_f32_16x16x32_bf16(a, b, acc3[t], 0, 0, 0);
    }
  }
#pragma unroll
  for (int t = 0; t < 7; t++) {
    const int o = t * 16 + c16;
    const float bias = b13p[o];
#pragma unroll
    for (int r = 0; r < 4; r++) {
      float v = acc3[t][r] + bias;
      v = fmaxf(v, 0.0f);
      x3s[wave][quad * 4 + r][o] = (bf16)v;
    }
  }
  for (int idx = lane; idx < 256; idx += 64)
    x3s[wave][idx >> 4][112 + (idx & 15)] = (bf16)0.0f;
  __syncthreads();

  // ---------------- Layer 4: (16x128) @ W2p^T -> 16x512 (+ part0) ----------------
  f32x4 acc4[32];
#pragma unroll
  for (int t = 0; t < 32; t++) acc4[t] = (f32x4){0.f, 0.f, 0.f, 0.f};
#pragma unroll
  for (int ks = 0; ks < 4; ks++) {
    const int k0 = ks * 32;
    bf16x8 a = *(const bf16x8*)&x3s[wave][c16][k0 + quad * 8];
    const bf16* bb = W2p + (size_t)c16 * 128 + k0 + quad * 8;
#pragma unroll
    for (int t = 0; t < 32; t++) {
      bf16x8 b = *(const bf16x8*)(bb + t * 16 * 128);
      acc4[t] = __builtin_amdgcn_mfma_f32_16x16x32_bf16(a, b, acc4[t], 0, 0, 0);
    }
  }

  float p0local = 0.0f;
#pragma unroll
  for (int t = 0; t < 32; t++) {
    const int o = t * 16 + c16;
    const float bias = b2p[o];
#pragma unroll
    for (int r = 0; r < 4; r++) {
      const int grow = m0 + quad * 4 + r;
      float v = acc4[t][r] + bias;
      out[(size_t)grow * 512 + o] = v;
      if (grow < N_ROWS - 1) {
        float nxt = input[(size_t)(grow + 1) * 512 + o];
        float d = v - nxt;
        p0local += d * d;
      }
    }
  }
  // wave reduce then one atomic per wave
#pragma unroll
  for (int off = 32; off > 0; off >>= 1) p0local += __shfl_down(p0local, off);
  if (lane == 0) atomicAdd(p0_accum, p0local);
}

// mu / S / part3 reductions over h. Block b covers rows [b*256, b*256+256).
__global__ void reduce_h(const float* __restrict__ h, float* __restrict__ acc) {
  __shared__ float redS[256];
  __shared__ float redP[256];
  const int t = threadIdx.x;
  const int r0 = blockIdx.x * 256;

  float prev = h[(size_t)r0 * 256 + t];
  float csum = prev;
  float s2 = prev * prev;
  float p3 = 0.0f;
  for (int r = 1; r < 256; r++) {
    float v = h[(size_t)(r0 + r) * 256 + t];
    csum += v;
    s2 += v * v;
    p3 += fabsf(v - prev);
    prev = v;
  }
  if (r0 + 256 < N_ROWS) {
    float v = h[(size_t)(r0 + 256) * 256 + t];
    p3 += fabsf(v - prev);
  }
  atomicAdd(&acc[t], csum);  // colsum[t]
  redS[t] = s2;
  redP[t] = p3;
  __syncthreads();
  for (int s = 128; s > 0; s >>= 1) {
    if (t < s) { redS[t] += redS[t + s]; redP[t] += redP[t + s]; }
    __syncthreads();
  }
  if (t == 0) {
    atomicAdd(&acc[257], redS[0]);
    atomicAdd(&acc[258], redP[0]);
  }
}

__global__ void finalize(const float* __restrict__ acc, float* __restrict__ out) {
  __shared__ float red[256];
  const int t = threadIdx.x;
  red[t] = fabsf(acc[t]);  // |colsum|
  __syncthreads();
  for (int s = 128; s > 0; s >>= 1) {
    if (t < s) red[t] += red[t + s];
    __syncthreads();
  }
  if (t == 0) {
    float part1 = red[0] / 65536.0f / 256.0f;
    float part0 = sqrtf(acc[256]) / 65535.0f;
    float part2 = fabsf(acc[257] / (65536.0f * 256.0f) - 1.0f);
    float part3 = acc[258] / (65535.0f * 256.0f);
    out[(size_t)N_ROWS * 512 + 0] = part0;
    out[(size_t)N_ROWS * 512 + 1] = part1;
    out[(size_t)N_ROWS * 512 + 2] = part2;
    out[(size_t)N_ROWS * 512 + 3] = part3;
  }
}

extern "C" void kernel_launch(void* const* d_in, const int* in_sizes, int n_in,
                              void* d_out, int out_size, void* d_ws, size_t ws_size,
                              hipStream_t stream) {
  const float* input = (const float*)d_in[0];
  const float* h   = (const float*)d_in[1];
  const float* W1  = (const float*)d_in[2];
  const float* b1  = (const float*)d_in[3];
  const float* W12 = (const float*)d_in[4];
  const float* b12 = (const float*)d_in[5];
  const float* W13 = (const float*)d_in[6];
  const float* b13 = (const float*)d_in[7];
  const float* W2  = (const float*)d_in[8];
  const float* b2  = (const float*)d_in[9];
  float* out = (float*)d_out;

  bf16* wp = (bf16*)d_ws;
  float* bp = (float*)((char*)d_ws + BP_OFF_BYTES);
  float* acc = (float*)((char*)d_ws + ACC_OFF_BYTES);

  hipMemsetAsync(acc, 0, ACC_FLOATS * sizeof(float), stream);
  pack_kernel<<<(WP_TOTAL + BP_FLOATS + 255) / 256, 256, 0, stream>>>(
      W1, b1, W12, b12, W13, b13, W2, b2, wp, bp);
  mlp_main<<<N_ROWS / 64, 256, 0, stream>>>(input, h, wp, bp, out, acc + 256);
  reduce_h<<<N_ROWS / 256, 256, 0, stream>>>(h, acc);
  finalize<<<1, 256, 0, stream>>>(acc, out);
}